// Round 1
// baseline (362.482 us; speedup 1.0000x reference)
//
#include <hip/hip_runtime.h>
#include <hip/hip_bf16.h>

// Sizes (fixed by the problem)
#define BB 2
#define NN 1024
#define DIM 512
#define HH 8
#define LL 8
#define DH 64
#define NROW 2048      // BB*NN
// exp(-d2/T) with T=0.1 -> exp2(C*d2), C = -10*log2(e)
#define CEXP (-14.4269504088896340736f)

// ---------------- K_A: normalize theta -> th [h*l][64] ----------------
__global__ __launch_bounds__(64) void k_theta_norm(const float* __restrict__ theta,
                                                   float* __restrict__ th) {
    int hl = blockIdx.x;          // 64
    int d  = threadIdx.x;         // 64
    float v = theta[hl * 64 + d];
    float s = v * v;
    #pragma unroll
    for (int off = 32; off; off >>= 1) s += __shfl_xor(s, off, 64);
    th[hl * 64 + d] = v / sqrtf(s);
}

// ---------------- K_B: Wqp[c][hl] = sum_d Wq[c][h*64+d]*th[h][l][d]; same for k ----
__global__ __launch_bounds__(64) void k_wproj(const float* __restrict__ Wqkv,
                                              const float* __restrict__ th,
                                              float* __restrict__ Wqp,
                                              float* __restrict__ Wkp) {
    __shared__ float th_s[64 * 65];   // padded
    int c = blockIdx.x;               // 512
    int t = threadIdx.x;              // 64  (= hl)
    for (int i = 0; i < 64; ++i) th_s[i * 65 + t] = th[i * 64 + t];
    __syncthreads();
    int h = t >> 3;
    const float* wq = Wqkv + c * 1536 + h * 64;
    const float* wk = wq + 512;
    const float* ts = th_s + t * 65;
    float aq = 0.f, ak = 0.f;
    #pragma unroll 4
    for (int d = 0; d < 64; ++d) {
        float tv = ts[d];
        aq = fmaf(wq[d], tv, aq);
        ak = fmaf(wk[d], tv, ak);
    }
    Wqp[c * 64 + t] = aq;
    Wkp[c * 64 + t] = ak;
}

// ---------------- K_C: qp/kp = scale * x @ W{q,k}p, layout [bh][l][n] ----------------
__global__ __launch_bounds__(256) void k_qkp(const float* __restrict__ x,
                                             const float* __restrict__ Wqp,
                                             const float* __restrict__ Wkp,
                                             float* __restrict__ qp,
                                             float* __restrict__ kp) {
    int o = blockIdx.x * 256 + threadIdx.x;  // 262144 = 2048 rows * 128 (64 q + 64 k)
    int row = o >> 7;
    int t   = o & 127;
    int hl  = t & 63;
    const float* Bm = (t & 64) ? Wkp : Wqp;
    const float4* x4 = (const float4*)(x + row * 512);
    float acc = 0.f;
    for (int c4 = 0; c4 < 128; ++c4) {
        float4 xv = x4[c4];
        const float* bp = Bm + (c4 * 4) * 64 + hl;
        acc = fmaf(xv.x, bp[0],   acc);
        acc = fmaf(xv.y, bp[64],  acc);
        acc = fmaf(xv.z, bp[128], acc);
        acc = fmaf(xv.w, bp[192], acc);
    }
    acc *= 0.125f;  // dim_head^-0.5
    int b = row >> 10, i = row & 1023, h = hl >> 3, l = hl & 7;
    float* dst = (t & 64) ? kp : qp;
    dst[((b * 8 + h) * 8 + l) * 1024 + i] = acc;
}

// ---------------- K_D: v = x @ Wv, layout [bh][n][64] ----------------
__global__ __launch_bounds__(256) void k_vproj(const float* __restrict__ x,
                                               const float* __restrict__ Wqkv,
                                               float* __restrict__ v) {
    int o = blockIdx.x * 256 + threadIdx.x;  // 131072
    int col = o & 511;
    int rq  = o >> 9;                        // [0,256)
    float acc[8] = {0.f, 0.f, 0.f, 0.f, 0.f, 0.f, 0.f, 0.f};
    const float4* x4 = (const float4*)x;
    const float* wp = Wqkv + 1024 + col;
    for (int c4 = 0; c4 < 128; ++c4) {
        float w0 = wp[(c4 * 4 + 0) * 1536];
        float w1 = wp[(c4 * 4 + 1) * 1536];
        float w2 = wp[(c4 * 4 + 2) * 1536];
        float w3 = wp[(c4 * 4 + 3) * 1536];
        #pragma unroll
        for (int s = 0; s < 8; ++s) {
            float4 a = x4[(rq + s * 256) * 128 + c4];
            acc[s] = fmaf(a.x, w0, fmaf(a.y, w1, fmaf(a.z, w2, fmaf(a.w, w3, acc[s]))));
        }
    }
    int h = col >> 6, d = col & 63;
    #pragma unroll
    for (int s = 0; s < 8; ++s) {
        int row = rq + s * 256;
        int b = row >> 10, i = row & 1023;
        v[((b * 8 + h) * 1024 + i) * 64 + d] = acc[s];
    }
}

// ---------------- K_E: attention rows (the big one) ----------------
// block = 256 thr (4 waves); wave owns 2 rows; attn row accumulators in registers.
__global__ __launch_bounds__(256) void k_attn(const float* __restrict__ qp,
                                              const float* __restrict__ kp,
                                              float* __restrict__ attn) {
    __shared__ float kp_s[8 * 1024];         // 32 KB
    int bx = blockIdx.x;                     // 2048
    int bh = bx >> 7;
    int rowbase = (bx & 127) * 8;
    int tid = threadIdx.x;
    int w = tid >> 6, lane = tid & 63;

    const float4* kp4 = (const float4*)(kp + bh * 8192);
    float4* kps4 = (float4*)kp_s;
    #pragma unroll
    for (int k = 0; k < 8; ++k) kps4[k * 256 + tid] = kp4[k * 256 + tid];

    int rA = rowbase + 2 * w;
    int rB = rA + 1;
    float qA[8], qB[8];
    #pragma unroll
    for (int l = 0; l < 8; ++l) {
        qA[l] = qp[bh * 8192 + l * 1024 + rA];
        qB[l] = qp[bh * 8192 + l * 1024 + rB];
    }
    __syncthreads();

    float accA[16], accB[16];
    #pragma unroll
    for (int m = 0; m < 16; ++m) { accA[m] = 0.f; accB[m] = 0.f; }

    for (int l = 0; l < 8; ++l) {
        float kv[16], kv2[16];
        #pragma unroll
        for (int m = 0; m < 16; ++m) {
            kv[m] = kp_s[l * 1024 + m * 64 + lane];
            kv2[m] = CEXP * kv[m] * kv[m];       // C*k^2
        }
        // row A: e' = exp2( (-2C q)*k + C k^2 ); exp2(C q^2) cancels in the ratio
        {
            float sq = -2.f * CEXP * qA[l];
            float e[16]; float s = 0.f;
            #pragma unroll
            for (int m = 0; m < 16; ++m) { e[m] = exp2f(fmaf(sq, kv[m], kv2[m])); s += e[m]; }
            #pragma unroll
            for (int off = 32; off; off >>= 1) s += __shfl_xor(s, off, 64);
            float inv = 0.125f * __builtin_amdgcn_rcpf(s);
            #pragma unroll
            for (int m = 0; m < 16; ++m) accA[m] = fmaf(e[m], inv, accA[m]);
        }
        // row B
        {
            float sq = -2.f * CEXP * qB[l];
            float e[16]; float s = 0.f;
            #pragma unroll
            for (int m = 0; m < 16; ++m) { e[m] = exp2f(fmaf(sq, kv[m], kv2[m])); s += e[m]; }
            #pragma unroll
            for (int off = 32; off; off >>= 1) s += __shfl_xor(s, off, 64);
            float inv = 0.125f * __builtin_amdgcn_rcpf(s);
            #pragma unroll
            for (int m = 0; m < 16; ++m) accB[m] = fmaf(e[m], inv, accB[m]);
        }
    }

    float* aA = attn + ((size_t)(bh * 1024 + rA)) * 1024 + lane;
    float* aB = attn + ((size_t)(bh * 1024 + rB)) * 1024 + lane;
    #pragma unroll
    for (int m = 0; m < 16; ++m) { aA[m * 64] = accA[m]; aB[m * 64] = accB[m]; }
}

// ---------------- K_F: out_head = attn @ v, layout [b][n][h*64+d] ----------------
__global__ __launch_bounds__(256) void k_av(const float* __restrict__ attn,
                                            const float* __restrict__ v,
                                            float* __restrict__ oh) {
    int o = blockIdx.x * 256 + threadIdx.x;  // 131072
    int d  = o & 63;
    int rq = (o >> 6) & 127;                 // [0,128)
    int bh = o >> 13;                        // [0,16)
    const float4* a4 = (const float4*)(attn + (size_t)bh * 1048576);
    const float* vp = v + bh * 65536 + d;
    float acc[8] = {0.f, 0.f, 0.f, 0.f, 0.f, 0.f, 0.f, 0.f};
    for (int j4 = 0; j4 < 256; ++j4) {
        int j = j4 * 4;
        float v0 = vp[(j + 0) * 64];
        float v1 = vp[(j + 1) * 64];
        float v2 = vp[(j + 2) * 64];
        float v3 = vp[(j + 3) * 64];
        #pragma unroll
        for (int s = 0; s < 8; ++s) {
            float4 a = a4[(rq + s * 128) * 256 + j4];
            acc[s] = fmaf(a.x, v0, fmaf(a.y, v1, fmaf(a.z, v2, fmaf(a.w, v3, acc[s]))));
        }
    }
    int b = bh >> 3, h = bh & 7;
    #pragma unroll
    for (int s = 0; s < 8; ++s) {
        int row = rq + s * 128;
        oh[(b * 1024 + row) * 512 + h * 64 + d] = acc[s];
    }
}

// ---------------- K_G: out = oh @ W_out + b_out ----------------
__global__ __launch_bounds__(256) void k_out(const float* __restrict__ oh,
                                             const float* __restrict__ Wout,
                                             const float* __restrict__ bout,
                                             float* __restrict__ out) {
    int o = blockIdx.x * 256 + threadIdx.x;  // 131072
    int col = o & 511;
    int rq  = o >> 9;                        // [0,256)
    float acc[8] = {0.f, 0.f, 0.f, 0.f, 0.f, 0.f, 0.f, 0.f};
    const float4* a4 = (const float4*)oh;
    const float* wp = Wout + col;
    for (int c4 = 0; c4 < 128; ++c4) {
        float w0 = wp[(c4 * 4 + 0) * 512];
        float w1 = wp[(c4 * 4 + 1) * 512];
        float w2 = wp[(c4 * 4 + 2) * 512];
        float w3 = wp[(c4 * 4 + 3) * 512];
        #pragma unroll
        for (int s = 0; s < 8; ++s) {
            float4 a = a4[(rq + s * 256) * 128 + c4];
            acc[s] = fmaf(a.x, w0, fmaf(a.y, w1, fmaf(a.z, w2, fmaf(a.w, w3, acc[s]))));
        }
    }
    float bias = bout[col];
    #pragma unroll
    for (int s = 0; s < 8; ++s) {
        int row = rq + s * 256;
        out[row * 512 + col] = acc[s] + bias;
    }
}

extern "C" void kernel_launch(void* const* d_in, const int* in_sizes, int n_in,
                              void* d_out, int out_size, void* d_ws, size_t ws_size,
                              hipStream_t stream) {
    const float* x     = (const float*)d_in[0];
    const float* Wqkv  = (const float*)d_in[1];
    const float* theta = (const float*)d_in[2];
    const float* Wout  = (const float*)d_in[3];
    const float* bout  = (const float*)d_in[4];

    float* out  = (float*)d_out;                  // [2,1024,512]
    float* attn = out + 2 * 1024 * 512;           // [2,8,1024,1024]

    float* ws  = (float*)d_ws;
    float* th  = ws;                 // 4096
    float* Wqp = ws + 4096;          // 32768
    float* Wkp = ws + 36864;         // 32768
    float* qp  = ws + 69632;         // 131072
    float* kp  = ws + 200704;        // 131072
    float* v   = ws + 331776;        // 1048576
    float* oh  = ws + 1380352;       // 1048576

    k_theta_norm<<<64,   64, 0, stream>>>(theta, th);
    k_wproj    <<<512,   64, 0, stream>>>(Wqkv, th, Wqp, Wkp);
    k_qkp      <<<1024, 256, 0, stream>>>(x, Wqp, Wkp, qp, kp);
    k_vproj    <<<512,  256, 0, stream>>>(x, Wqkv, v);
    k_attn     <<<2048, 256, 0, stream>>>(qp, kp, attn);
    k_av       <<<512,  256, 0, stream>>>(attn, v, oh);
    k_out      <<<512,  256, 0, stream>>>(oh, Wout, bout, out);
}

// Round 2
// 269.997 us; speedup vs baseline: 1.3425x; 1.3425x over previous
//
#include <hip/hip_runtime.h>
#include <hip/hip_bf16.h>

// Sizes (fixed by the problem)
#define BB 2
#define NN 1024
#define DIM 512
#define HH 8
#define LL 8
#define DH 64
// exp(-d2/T) with T=0.1 -> exp2(C*d2), C = -10*log2(e)
#define CEXP (-14.4269504088896340736f)

// ---------------- K_B: Wqp[c][hl] = sum_d Wq[c][h*64+d]*th_hat[h][l][d] ----------
// theta normalization fused: accumulate with raw theta, scale by rsqrt(sumsq) at end.
__global__ __launch_bounds__(64) void k_wproj(const float* __restrict__ Wqkv,
                                              const float* __restrict__ theta,
                                              float* __restrict__ Wqp,
                                              float* __restrict__ Wkp) {
    __shared__ float th_s[64 * 65];   // padded
    int c = blockIdx.x;               // 512
    int t = threadIdx.x;              // 64  (= hl)
    for (int i = 0; i < 64; ++i) th_s[i * 65 + t] = theta[i * 64 + t];
    __syncthreads();
    const float* ts = th_s + t * 65;
    float ss = 0.f;
    #pragma unroll 8
    for (int d = 0; d < 64; ++d) ss = fmaf(ts[d], ts[d], ss);
    float inv = rsqrtf(ss);
    int h = t >> 3;
    const float* wq = Wqkv + c * 1536 + h * 64;
    const float* wk = wq + 512;
    float aq = 0.f, ak = 0.f;
    #pragma unroll 4
    for (int d = 0; d < 64; ++d) {
        float tv = ts[d];
        aq = fmaf(wq[d], tv, aq);
        ak = fmaf(wk[d], tv, ak);
    }
    Wqp[c * 64 + t] = aq * inv;
    Wkp[c * 64 + t] = ak * inv;
}

// ---------------- K_C: qp/kp = scale * x @ W{q,k}p, layout [bh][l][n] ----------------
__global__ __launch_bounds__(256) void k_qkp(const float* __restrict__ x,
                                             const float* __restrict__ Wqp,
                                             const float* __restrict__ Wkp,
                                             float* __restrict__ qp,
                                             float* __restrict__ kp) {
    int o = blockIdx.x * 256 + threadIdx.x;  // 262144 = 2048 rows * 128 (64 q + 64 k)
    int row = o >> 7;
    int t   = o & 127;
    int hl  = t & 63;
    const float* Bm = (t & 64) ? Wkp : Wqp;
    const float4* x4 = (const float4*)(x + row * 512);
    float a0 = 0.f, a1 = 0.f, a2 = 0.f, a3 = 0.f;
    for (int c4 = 0; c4 < 128; ++c4) {
        float4 xv = x4[c4];
        const float* bp = Bm + (c4 * 4) * 64 + hl;
        a0 = fmaf(xv.x, bp[0],   a0);
        a1 = fmaf(xv.y, bp[64],  a1);
        a2 = fmaf(xv.z, bp[128], a2);
        a3 = fmaf(xv.w, bp[192], a3);
    }
    float acc = ((a0 + a1) + (a2 + a3)) * 0.125f;  // dim_head^-0.5
    int b = row >> 10, i = row & 1023, h = hl >> 3, l = hl & 7;
    float* dst = (t & 64) ? kp : qp;
    dst[((b * 8 + h) * 8 + l) * 1024 + i] = acc;
}

// ---------------- K_D: v = x @ Wv, layout [bh][n][64]; 4 rows/thread ----------------
__global__ __launch_bounds__(256) void k_vproj(const float* __restrict__ x,
                                               const float* __restrict__ Wqkv,
                                               float* __restrict__ v) {
    int o = blockIdx.x * 256 + threadIdx.x;  // 262144
    int col = o & 511;
    int rq  = o >> 9;                        // [0,512)
    float acc[4] = {0.f, 0.f, 0.f, 0.f};
    const float4* x4 = (const float4*)x;
    const float* wp = Wqkv + 1024 + col;
    for (int c4 = 0; c4 < 128; ++c4) {
        float w0 = wp[(c4 * 4 + 0) * 1536];
        float w1 = wp[(c4 * 4 + 1) * 1536];
        float w2 = wp[(c4 * 4 + 2) * 1536];
        float w3 = wp[(c4 * 4 + 3) * 1536];
        #pragma unroll
        for (int s = 0; s < 4; ++s) {
            float4 a = x4[(rq + s * 512) * 128 + c4];
            acc[s] = fmaf(a.x, w0, fmaf(a.y, w1, fmaf(a.z, w2, fmaf(a.w, w3, acc[s]))));
        }
    }
    int h = col >> 6, d = col & 63;
    #pragma unroll
    for (int s = 0; s < 4; ++s) {
        int row = rq + s * 512;
        int b = row >> 10, i = row & 1023;
        v[((b * 8 + h) * 1024 + i) * 64 + d] = acc[s];
    }
}

// ---------------- K_E: fused attention rows + PV ----------------
// block = 256 thr (4 waves); wave owns 2 rows; attn row accumulators in registers.
// Phase 1: per-slice softmax, average -> attn rows (regs) -> global + LDS.
// Phase 2: oh[rows][64] = attn_rows @ v  (P from LDS broadcast, v from L2).
__global__ __launch_bounds__(256) void k_attn_pv(const float* __restrict__ qp,
                                                 const float* __restrict__ kp,
                                                 const float* __restrict__ v,
                                                 float* __restrict__ attn,
                                                 float* __restrict__ oh) {
    __shared__ float s_buf[8 * 1024];        // 32 KB: kp during phase 1, P rows in phase 2
    int bx = blockIdx.x;                     // 2048
    int bh = bx >> 7;
    int rowbase = (bx & 127) * 8;
    int tid = threadIdx.x;
    int w = tid >> 6, lane = tid & 63;

    const float4* kp4 = (const float4*)(kp + bh * 8192);
    float4* kps4 = (float4*)s_buf;
    #pragma unroll
    for (int k = 0; k < 8; ++k) kps4[k * 256 + tid] = kp4[k * 256 + tid];

    int rA = rowbase + 2 * w;
    int rB = rA + 1;
    float qA[8], qB[8];
    #pragma unroll
    for (int l = 0; l < 8; ++l) {
        qA[l] = qp[bh * 8192 + l * 1024 + rA];
        qB[l] = qp[bh * 8192 + l * 1024 + rB];
    }
    __syncthreads();

    float accA[16], accB[16];
    #pragma unroll
    for (int m = 0; m < 16; ++m) { accA[m] = 0.f; accB[m] = 0.f; }

    for (int l = 0; l < 8; ++l) {
        float kv[16], kv2[16];
        #pragma unroll
        for (int m = 0; m < 16; ++m) {
            kv[m] = s_buf[l * 1024 + m * 64 + lane];
            kv2[m] = CEXP * kv[m] * kv[m];       // C*k^2
        }
        // e' = exp2( (-2C q)*k + C k^2 ); exp2(C q^2) cancels in the softmax ratio
        {
            float sq = -2.f * CEXP * qA[l];
            float e[16]; float s = 0.f;
            #pragma unroll
            for (int m = 0; m < 16; ++m) { e[m] = __builtin_amdgcn_exp2f(fmaf(sq, kv[m], kv2[m])); s += e[m]; }
            #pragma unroll
            for (int off = 32; off; off >>= 1) s += __shfl_xor(s, off, 64);
            float inv = 0.125f * __builtin_amdgcn_rcpf(s);
            #pragma unroll
            for (int m = 0; m < 16; ++m) accA[m] = fmaf(e[m], inv, accA[m]);
        }
        {
            float sq = -2.f * CEXP * qB[l];
            float e[16]; float s = 0.f;
            #pragma unroll
            for (int m = 0; m < 16; ++m) { e[m] = __builtin_amdgcn_exp2f(fmaf(sq, kv[m], kv2[m])); s += e[m]; }
            #pragma unroll
            for (int off = 32; off; off >>= 1) s += __shfl_xor(s, off, 64);
            float inv = 0.125f * __builtin_amdgcn_rcpf(s);
            #pragma unroll
            for (int m = 0; m < 16; ++m) accB[m] = fmaf(e[m], inv, accB[m]);
        }
    }

    // write attn rows to global
    float* aA = attn + ((size_t)(bh * 1024 + rA)) * 1024 + lane;
    float* aB = attn + ((size_t)(bh * 1024 + rB)) * 1024 + lane;
    #pragma unroll
    for (int m = 0; m < 16; ++m) { aA[m * 64] = accA[m]; aB[m * 64] = accB[m]; }

    __syncthreads();   // all waves done with kp in s_buf
    // stash P rows in LDS: row (2w), (2w+1); col m*64+lane
    #pragma unroll
    for (int m = 0; m < 16; ++m) {
        s_buf[(2 * w) * 1024 + m * 64 + lane]     = accA[m];
        s_buf[(2 * w + 1) * 1024 + m * 64 + lane] = accB[m];
    }
    __syncthreads();

    // Phase 2: oh rows = P @ v. thread -> d = lane, rows 2*rp, 2*rp+1
    int d  = lane;
    int rp = w;                              // wave w handles rows 2w, 2w+1 (matches any mapping; all rows in LDS)
    const float* p0 = s_buf + (2 * rp) * 1024;
    const float* p1 = p0 + 1024;
    const float* vp = v + bh * 65536 + d;
    float o0[4] = {0.f, 0.f, 0.f, 0.f};
    float o1[4] = {0.f, 0.f, 0.f, 0.f};
    for (int j = 0; j < 1024; j += 4) {
        float4 a0 = *(const float4*)(p0 + j);
        float4 a1 = *(const float4*)(p1 + j);
        float v0 = vp[(j + 0) * 64];
        float v1 = vp[(j + 1) * 64];
        float v2 = vp[(j + 2) * 64];
        float v3 = vp[(j + 3) * 64];
        o0[0] = fmaf(a0.x, v0, o0[0]); o0[1] = fmaf(a0.y, v1, o0[1]);
        o0[2] = fmaf(a0.z, v2, o0[2]); o0[3] = fmaf(a0.w, v3, o0[3]);
        o1[0] = fmaf(a1.x, v0, o1[0]); o1[1] = fmaf(a1.y, v1, o1[1]);
        o1[2] = fmaf(a1.z, v2, o1[2]); o1[3] = fmaf(a1.w, v3, o1[3]);
    }
    int b = bh >> 3, h = bh & 7;
    int r0 = rowbase + 2 * rp, r1 = r0 + 1;
    oh[(b * 1024 + r0) * 512 + h * 64 + d] = (o0[0] + o0[1]) + (o0[2] + o0[3]);
    oh[(b * 1024 + r1) * 512 + h * 64 + d] = (o1[0] + o1[1]) + (o1[2] + o1[3]);
}

// ---------------- K_G: out = oh @ W_out + b_out; 4 rows/thread ----------------
__global__ __launch_bounds__(256) void k_out(const float* __restrict__ oh,
                                             const float* __restrict__ Wout,
                                             const float* __restrict__ bout,
                                             float* __restrict__ out) {
    int o = blockIdx.x * 256 + threadIdx.x;  // 262144
    int col = o & 511;
    int rq  = o >> 9;                        // [0,512)
    float acc[4] = {0.f, 0.f, 0.f, 0.f};
    const float4* a4 = (const float4*)oh;
    const float* wp = Wout + col;
    for (int c4 = 0; c4 < 128; ++c4) {
        float w0 = wp[(c4 * 4 + 0) * 512];
        float w1 = wp[(c4 * 4 + 1) * 512];
        float w2 = wp[(c4 * 4 + 2) * 512];
        float w3 = wp[(c4 * 4 + 3) * 512];
        #pragma unroll
        for (int s = 0; s < 4; ++s) {
            float4 a = a4[(rq + s * 512) * 128 + c4];
            acc[s] = fmaf(a.x, w0, fmaf(a.y, w1, fmaf(a.z, w2, fmaf(a.w, w3, acc[s]))));
        }
    }
    float bias = bout[col];
    #pragma unroll
    for (int s = 0; s < 4; ++s) {
        int row = rq + s * 512;
        out[row * 512 + col] = acc[s] + bias;
    }
}

extern "C" void kernel_launch(void* const* d_in, const int* in_sizes, int n_in,
                              void* d_out, int out_size, void* d_ws, size_t ws_size,
                              hipStream_t stream) {
    const float* x     = (const float*)d_in[0];
    const float* Wqkv  = (const float*)d_in[1];
    const float* theta = (const float*)d_in[2];
    const float* Wout  = (const float*)d_in[3];
    const float* bout  = (const float*)d_in[4];

    float* out  = (float*)d_out;                  // [2,1024,512]
    float* attn = out + 2 * 1024 * 512;           // [2,8,1024,1024]

    float* ws  = (float*)d_ws;
    float* Wqp = ws;                 // 32768
    float* Wkp = ws + 32768;         // 32768
    float* qp  = ws + 65536;         // 131072
    float* kp  = ws + 196608;        // 131072
    float* v   = ws + 327680;        // 1048576
    float* oh  = ws + 1376256;       // 1048576

    k_wproj   <<<512,   64, 0, stream>>>(Wqkv, theta, Wqp, Wkp);
    k_qkp     <<<1024, 256, 0, stream>>>(x, Wqp, Wkp, qp, kp);
    k_vproj   <<<1024, 256, 0, stream>>>(x, Wqkv, v);
    k_attn_pv <<<2048, 256, 0, stream>>>(qp, kp, v, attn, oh);
    k_out     <<<1024, 256, 0, stream>>>(oh, Wout, bout, out);
}

// Round 3
// 259.272 us; speedup vs baseline: 1.3981x; 1.0414x over previous
//
#include <hip/hip_runtime.h>
#include <hip/hip_bf16.h>

// Sizes (fixed): b=2, n=1024, dim=512, h=8, L=8, dh=64
// exp(-d2/T) with T=0.1 -> exp2(C*d2), C = -10*log2(e)
#define CEXP (-14.4269504088896340736f)

typedef __attribute__((ext_vector_type(8))) short bfrag8;   // 8 bf16 (4 VGPR) MFMA operand
typedef __attribute__((ext_vector_type(4))) float fvec4;    // MFMA accumulator

__device__ inline unsigned short f2bf(float f) {            // RNE float->bf16
    unsigned u = __builtin_bit_cast(unsigned, f);
    u += 0x7fffu + ((u >> 16) & 1u);
    return (unsigned short)(u >> 16);
}
__device__ inline float bf2f(unsigned short h) {
    unsigned u = ((unsigned)h) << 16;
    return __builtin_bit_cast(float, u);
}

// ---------------- K_B: Wqp[c][hl] = sum_d Wq[c][h*64+d]*th_hat[h][l][d] ----------
__global__ __launch_bounds__(64) void k_wproj(const float* __restrict__ Wqkv,
                                              const float* __restrict__ theta,
                                              float* __restrict__ Wqp,
                                              float* __restrict__ Wkp) {
    __shared__ float th_s[64 * 65];   // padded
    int c = blockIdx.x;               // 512
    int t = threadIdx.x;              // 64  (= hl)
    for (int i = 0; i < 64; ++i) th_s[i * 65 + t] = theta[i * 64 + t];
    __syncthreads();
    const float* ts = th_s + t * 65;
    float ss = 0.f;
    #pragma unroll 8
    for (int d = 0; d < 64; ++d) ss = fmaf(ts[d], ts[d], ss);
    float inv = rsqrtf(ss);
    int h = t >> 3;
    const float* wq = Wqkv + c * 1536 + h * 64;
    const float* wk = wq + 512;
    float aq = 0.f, ak = 0.f;
    #pragma unroll 4
    for (int d = 0; d < 64; ++d) {
        float tv = ts[d];
        aq = fmaf(wq[d], tv, aq);
        ak = fmaf(wk[d], tv, ak);
    }
    Wqp[c * 64 + t] = aq * inv;
    Wkp[c * 64 + t] = ak * inv;
}

// ---------------- K_C: qp/kp = scale * x @ W{q,k}p, layout [bh][l][n] ----------------
__global__ __launch_bounds__(256) void k_qkp(const float* __restrict__ x,
                                             const float* __restrict__ Wqp,
                                             const float* __restrict__ Wkp,
                                             float* __restrict__ qp,
                                             float* __restrict__ kp) {
    int o = blockIdx.x * 256 + threadIdx.x;  // 262144 = 2048 rows * 128 (64 q + 64 k)
    int row = o >> 7;
    int t   = o & 127;
    int hl  = t & 63;
    const float* Bm = (t & 64) ? Wkp : Wqp;
    const float4* x4 = (const float4*)(x + row * 512);
    float a0 = 0.f, a1 = 0.f, a2 = 0.f, a3 = 0.f;
    for (int c4 = 0; c4 < 128; ++c4) {
        float4 xv = x4[c4];
        const float* bp = Bm + (c4 * 4) * 64 + hl;
        a0 = fmaf(xv.x, bp[0],   a0);
        a1 = fmaf(xv.y, bp[64],  a1);
        a2 = fmaf(xv.z, bp[128], a2);
        a3 = fmaf(xv.w, bp[192], a3);
    }
    float acc = ((a0 + a1) + (a2 + a3)) * 0.125f;  // dim_head^-0.5
    int b = row >> 10, i = row & 1023, h = hl >> 3, l = hl & 7;
    float* dst = (t & 64) ? kp : qp;
    dst[((b * 8 + h) * 8 + l) * 1024 + i] = acc;
}

// ---------------- K_D: vT = (x @ Wv)^T as bf16 hi/lo, layout [bh][d][n] ----------------
__global__ __launch_bounds__(256) void k_vproj(const float* __restrict__ x,
                                               const float* __restrict__ Wqkv,
                                               unsigned short* __restrict__ vThi,
                                               unsigned short* __restrict__ vTlo) {
    int o = blockIdx.x * 256 + threadIdx.x;  // 131072
    int col = o & 511;
    int rq  = o >> 9;                        // [0,256)
    float acc[8] = {0.f, 0.f, 0.f, 0.f, 0.f, 0.f, 0.f, 0.f};
    const float4* x4 = (const float4*)x;
    const float* wp = Wqkv + 1024 + col;
    for (int c4 = 0; c4 < 128; ++c4) {
        float w0 = wp[(c4 * 4 + 0) * 1536];
        float w1 = wp[(c4 * 4 + 1) * 1536];
        float w2 = wp[(c4 * 4 + 2) * 1536];
        float w3 = wp[(c4 * 4 + 3) * 1536];
        #pragma unroll
        for (int s = 0; s < 8; ++s) {
            float4 a = x4[(rq + s * 256) * 128 + c4];
            acc[s] = fmaf(a.x, w0, fmaf(a.y, w1, fmaf(a.z, w2, fmaf(a.w, w3, acc[s]))));
        }
    }
    int h = col >> 6, d = col & 63;
    #pragma unroll
    for (int s = 0; s < 8; ++s) {
        int row = rq + s * 256;
        int b = row >> 10, i = row & 1023;
        size_t off = (size_t)(b * 8 + h) * 65536 + (size_t)d * 1024 + i;
        unsigned short hi = f2bf(acc[s]);
        vThi[off] = hi;
        vTlo[off] = f2bf(acc[s] - bf2f(hi));
    }
}

// ---------------- K_E: fused attention rows + MFMA PV ----------------
// block = 256 thr (4 waves); wave owns 2 rows in phase 1.
// Phase 1: per-slice softmax, average -> attn rows (regs) -> global; bf16 hi/lo -> LDS.
// Phase 2: oh = P @ v via mfma 16x16x32 bf16. A-tile rows 0-7 = P_hi, rows 8-15 = P_lo;
//          two passes (B = Vhi, Vlo); oh row = C[r] + C[r+8] (shfl_xor 32).
__global__ __launch_bounds__(256) void k_attn_pv(const float* __restrict__ qp,
                                                 const float* __restrict__ kp,
                                                 const unsigned short* __restrict__ vThi,
                                                 const unsigned short* __restrict__ vTlo,
                                                 float* __restrict__ attn,
                                                 float* __restrict__ oh) {
    __shared__ float s_buf[8 * 1024];        // 32 KB: kp (f32) phase 1; P hi/lo (bf16 [16][1024]) phase 2
    int bx = blockIdx.x;                     // 2048
    int bh = bx >> 7;
    int rowbase = (bx & 127) * 8;
    int tid = threadIdx.x;
    int w = tid >> 6, lane = tid & 63;

    const float4* kp4 = (const float4*)(kp + bh * 8192);
    float4* kps4 = (float4*)s_buf;
    #pragma unroll
    for (int k = 0; k < 8; ++k) kps4[k * 256 + tid] = kp4[k * 256 + tid];

    int rA = rowbase + 2 * w;
    int rB = rA + 1;
    float qA[8], qB[8];
    #pragma unroll
    for (int l = 0; l < 8; ++l) {
        qA[l] = qp[bh * 8192 + l * 1024 + rA];
        qB[l] = qp[bh * 8192 + l * 1024 + rB];
    }
    __syncthreads();

    float accA[16], accB[16];
    #pragma unroll
    for (int m = 0; m < 16; ++m) { accA[m] = 0.f; accB[m] = 0.f; }

    for (int l = 0; l < 8; ++l) {
        float kv[16], kv2[16];
        #pragma unroll
        for (int m = 0; m < 16; ++m) {
            kv[m] = s_buf[l * 1024 + m * 64 + lane];
            kv2[m] = CEXP * kv[m] * kv[m];       // C*k^2
        }
        // e' = exp2( (-2C q)*k + C k^2 ); exp2(C q^2) cancels in the softmax ratio
        {
            float sq = -2.f * CEXP * qA[l];
            float e[16]; float s = 0.f;
            #pragma unroll
            for (int m = 0; m < 16; ++m) { e[m] = __builtin_amdgcn_exp2f(fmaf(sq, kv[m], kv2[m])); s += e[m]; }
            #pragma unroll
            for (int off = 32; off; off >>= 1) s += __shfl_xor(s, off, 64);
            float inv = 0.125f * __builtin_amdgcn_rcpf(s);
            #pragma unroll
            for (int m = 0; m < 16; ++m) accA[m] = fmaf(e[m], inv, accA[m]);
        }
        {
            float sq = -2.f * CEXP * qB[l];
            float e[16]; float s = 0.f;
            #pragma unroll
            for (int m = 0; m < 16; ++m) { e[m] = __builtin_amdgcn_exp2f(fmaf(sq, kv[m], kv2[m])); s += e[m]; }
            #pragma unroll
            for (int off = 32; off; off >>= 1) s += __shfl_xor(s, off, 64);
            float inv = 0.125f * __builtin_amdgcn_rcpf(s);
            #pragma unroll
            for (int m = 0; m < 16; ++m) accB[m] = fmaf(e[m], inv, accB[m]);
        }
    }

    // write attn rows to global (f32, exact)
    float* aA = attn + ((size_t)(bh * 1024 + rA)) * 1024 + lane;
    float* aB = attn + ((size_t)(bh * 1024 + rB)) * 1024 + lane;
    #pragma unroll
    for (int m = 0; m < 16; ++m) { aA[m * 64] = accA[m]; aB[m * 64] = accB[m]; }

    __syncthreads();   // all waves done reading kp from s_buf

    // stash P as bf16 hi (rows 0-7) / lo (rows 8-15), XOR-swizzled: idx = r*1024 + (j ^ ((r&7)<<3))
    unsigned short* ps = (unsigned short*)s_buf;
    int lrA = 2 * w, lrB = lrA + 1;
    int swzA = lrA << 3, swzB = lrB << 3;    // (r&7)<<3, r<8
    #pragma unroll
    for (int m = 0; m < 16; ++m) {
        int j = m * 64 + lane;
        unsigned short hA = f2bf(accA[m]);
        unsigned short hB = f2bf(accB[m]);
        ps[lrA * 1024 + (j ^ swzA)]       = hA;
        ps[lrB * 1024 + (j ^ swzB)]       = hB;
        ps[(lrA + 8) * 1024 + (j ^ swzA)] = f2bf(accA[m] - bf2f(hA));
        ps[(lrB + 8) * 1024 + (j ^ swzB)] = f2bf(accB[m] - bf2f(hB));
    }
    __syncthreads();

    // Phase 2: wave w computes oh cols n0..n0+15 over full K=1024.
    int n0 = w * 16;
    int ar  = lane & 15;                     // A row
    int asw = (ar & 7) << 3;
    int ak  = (lane >> 4) * 8;               // A k-subchunk
    const unsigned short* ap = ps + ar * 1024;
    size_t boff = (size_t)bh * 65536 + (size_t)(n0 + (lane & 15)) * 1024 + ak;
    const unsigned short* bh_p = vThi + boff;
    const unsigned short* bl_p = vTlo + boff;
    fvec4 acc = {0.f, 0.f, 0.f, 0.f};
    #pragma unroll 4
    for (int s = 0; s < 32; ++s) {
        bfrag8 a  = *(const bfrag8*)(ap + ((s * 32 + ak) ^ asw));
        bfrag8 vh = *(const bfrag8*)(bh_p + s * 32);
        bfrag8 vl = *(const bfrag8*)(bl_p + s * 32);
        acc = __builtin_amdgcn_mfma_f32_16x16x32_bf16(a, vh, acc, 0, 0, 0);
        acc = __builtin_amdgcn_mfma_f32_16x16x32_bf16(a, vl, acc, 0, 0, 0);
    }
    int b = bh >> 3, h = bh & 7;
    #pragma unroll
    for (int q = 0; q < 4; ++q) {
        float t = acc[q] + __shfl_xor(acc[q], 32);   // C[r] + C[r+8]
        if (lane < 32) {
            int row = rowbase + (lane >> 4) * 4 + q;
            oh[(b * 1024 + row) * 512 + h * 64 + n0 + (lane & 15)] = t;
        }
    }
}

// ---------------- K_G: out = oh @ W_out + b_out; 8 rows/thread ----------------
__global__ __launch_bounds__(256) void k_out(const float* __restrict__ oh,
                                             const float* __restrict__ Wout,
                                             const float* __restrict__ bout,
                                             float* __restrict__ out) {
    int o = blockIdx.x * 256 + threadIdx.x;  // 131072
    int col = o & 511;
    int rq  = o >> 9;                        // [0,256)
    float acc[8] = {0.f, 0.f, 0.f, 0.f, 0.f, 0.f, 0.f, 0.f};
    const float4* a4 = (const float4*)oh;
    const float* wp = Wout + col;
    for (int c4 = 0; c4 < 128; ++c4) {
        float w0 = wp[(c4 * 4 + 0) * 512];
        float w1 = wp[(c4 * 4 + 1) * 512];
        float w2 = wp[(c4 * 4 + 2) * 512];
        float w3 = wp[(c4 * 4 + 3) * 512];
        #pragma unroll
        for (int s = 0; s < 8; ++s) {
            float4 a = a4[(rq + s * 256) * 128 + c4];
            acc[s] = fmaf(a.x, w0, fmaf(a.y, w1, fmaf(a.z, w2, fmaf(a.w, w3, acc[s]))));
        }
    }
    float bias = bout[col];
    #pragma unroll
    for (int s = 0; s < 8; ++s) {
        int row = rq + s * 256;
        out[row * 512 + col] = acc[s] + bias;
    }
}

extern "C" void kernel_launch(void* const* d_in, const int* in_sizes, int n_in,
                              void* d_out, int out_size, void* d_ws, size_t ws_size,
                              hipStream_t stream) {
    const float* x     = (const float*)d_in[0];
    const float* Wqkv  = (const float*)d_in[1];
    const float* theta = (const float*)d_in[2];
    const float* Wout  = (const float*)d_in[3];
    const float* bout  = (const float*)d_in[4];

    float* out  = (float*)d_out;                  // [2,1024,512]
    float* attn = out + 2 * 1024 * 512;           // [2,8,1024,1024]

    float* ws  = (float*)d_ws;
    float* Wqp = ws;                               // 32768
    float* Wkp = ws + 32768;                       // 32768
    float* qp  = ws + 65536;                       // 131072
    float* kp  = ws + 196608;                      // 131072
    unsigned short* vThi = (unsigned short*)(ws + 327680);   // 1,048,576 u16 = 524288 f
    unsigned short* vTlo = (unsigned short*)(ws + 851968);   // 1,048,576 u16
    float* oh  = ws + 1376256;                     // 1048576

    k_wproj   <<<512,   64, 0, stream>>>(Wqkv, theta, Wqp, Wkp);
    k_qkp     <<<1024, 256, 0, stream>>>(x, Wqp, Wkp, qp, kp);
    k_vproj   <<<512,  256, 0, stream>>>(x, Wqkv, vThi, vTlo);
    k_attn_pv <<<2048, 256, 0, stream>>>(qp, kp, vThi, vTlo, attn, oh);
    k_out     <<<512,  256, 0, stream>>>(oh, Wout, bout, out);
}